// Round 1
// baseline (202.734 us; speedup 1.0000x reference)
//
#include <hip/hip_runtime.h>
#include <hip/hip_bf16.h>

// Problem constants
#define Bb    32
#define CO    128
#define CI    128
#define HW    56
#define NPIX  3136   // 56*56
#define PH    58
#define PPIX  3364   // 58*58
#define NT    25     // ceil(3136/128)

typedef __bf16 bf16x8 __attribute__((ext_vector_type(8)));
typedef float  f32x4  __attribute__((ext_vector_type(4)));

__device__ __forceinline__ void glds16(const void* g, void* l) {
  __builtin_amdgcn_global_load_lds(
      (const __attribute__((address_space(1))) void*)g,
      (__attribute__((address_space(3))) void*)l, 16, 0, 0);
}

// ---------------------------------------------------------------------------
// Prep 1: wt[b][p][co][ci] = bf16( eps[b][co][ci][p] * exp(psi[co][ci][p]) + mu[...] )
// 4,718,592 elements, one per thread. Writes coalesced (ci contiguous).
// ---------------------------------------------------------------------------
__global__ void prep_weights(const float* __restrict__ eps,
                             const float* __restrict__ psi,
                             const float* __restrict__ mu,
                             __bf16* __restrict__ wt) {
  int idx = blockIdx.x * 256 + threadIdx.x;
  int ci = idx & 127;
  int co = (idx >> 7) & 127;
  int t  = idx >> 14;         // = b*9 + p, < 288
  int p  = t % 9;
  int b  = t / 9;
  int src  = ((b * CO + co) * CI + ci) * 9 + p;
  int wsrc = (co * CI + ci) * 9 + p;
  float w = eps[src] * __expf(psi[wsrc]) + mu[wsrc];
  wt[idx] = (__bf16)w;
}

// ---------------------------------------------------------------------------
// Prep 2a: zero the padded border of inp_t (228 border pixels per batch, 256B each)
// 116,736 16B-chunks = 456 blocks * 256 threads.
// ---------------------------------------------------------------------------
__global__ void border_zero(__bf16* __restrict__ it) {
  int cid = blockIdx.x * 256 + threadIdx.x;
  int pid = cid >> 4;        // border pixel id 0..7295
  int chunk = cid & 15;
  int b = pid / 228;
  int e = pid - b * 228;
  int ph, pw;
  if (e < 58)       { ph = 0;       pw = e; }
  else if (e < 116) { ph = 57;      pw = e - 58; }
  else if (e < 172) { ph = e - 115; pw = 0; }      // rows 1..56, col 0
  else              { ph = e - 171; pw = 57; }     // rows 1..56, col 57
  f32x4 z = {0.f, 0.f, 0.f, 0.f};
  *(f32x4*)&it[((size_t)b * PPIX + ph * PH + pw) * CI + chunk * 8] = z;
}

// ---------------------------------------------------------------------------
// Prep 2b: inp_t[b][(ih+1)*58+(iw+1)][ci] = bf16(input[b][ci][ih][iw])
// LDS-tiled transpose: block = (64-pixel strip, all 128 ci) of one batch.
// ---------------------------------------------------------------------------
__global__ void transpose_pad(const float* __restrict__ in, __bf16* __restrict__ it) {
  __shared__ __align__(16) __bf16 T[64][136];   // +8 pad vs 128
  int tid = threadIdx.x;
  int p0 = blockIdx.x * 64;
  int b  = blockIdx.y;
  const float* src = in + (size_t)b * CI * NPIX;
#pragma unroll
  for (int j = 0; j < 8; ++j) {
    int c = j * 256 + tid;
    int ci = c >> 4, xc = c & 15;
    float4 v = *(const float4*)(src + (size_t)ci * NPIX + p0 + xc * 4);
    T[xc * 4 + 0][ci] = (__bf16)v.x;
    T[xc * 4 + 1][ci] = (__bf16)v.y;
    T[xc * 4 + 2][ci] = (__bf16)v.z;
    T[xc * 4 + 3][ci] = (__bf16)v.w;
  }
  __syncthreads();
  __bf16* dstb = it + (size_t)b * PPIX * CI;
#pragma unroll
  for (int j = 0; j < 4; ++j) {
    int c = j * 256 + tid;
    int pl = c >> 4, xc = c & 15;
    int pix = p0 + pl;
    int oh = pix / 56, ow = pix - oh * 56;
    int ppix = (oh + 1) * PH + (ow + 1);
    *(f32x4*)&dstb[(size_t)ppix * CI + xc * 8] = *(const f32x4*)&T[pl][xc * 8];
  }
}

// ---------------------------------------------------------------------------
// GEMM: out[b][co][n] = sum_{p,ci} wt[b][p][co][ci] * inp_t[b][pix(n,p)][ci]
// 128x128 tile per block, 4 waves of 64x64, mfma_f32_16x16x32_bf16.
// LDS fragment-order layout [ko(4)][row(128)][8] -> all ds_read_b128;
// staging is pure global_load_lds (16B), zero per-element VALU.
// ---------------------------------------------------------------------------
__global__ __launch_bounds__(256) void bconv_gemm(
    const __bf16* __restrict__ wt,   // [b][9][128 co][128 ci]
    const __bf16* __restrict__ it,   // [b][3364 pix][128 ci]
    float* __restrict__ out) {       // [b][128 co][3136 n]
  __shared__ __align__(16) __bf16 As[4096];   // [ko][co][8]
  __shared__ __align__(16) __bf16 Bs[4096];   // [ko][n ][8]
  const int tid  = threadIdx.x;
  const int w    = tid >> 6;
  const int lane = tid & 63;
  const int quad = lane >> 4;
  const int l15  = lane & 15;
  const int b  = blockIdx.y;
  const int nt = blockIdx.x;

  // Padded-pixel base for the two staging rows this lane covers (n = lane, lane+64).
  int pixb[2];
#pragma unroll
  for (int q = 0; q < 2; ++q) {
    int n = nt * 128 + q * 64 + lane;
    if (n > NPIX - 1) n = NPIX - 1;          // clamp tail tile (dup last pixel, masked at store)
    int oh = n / 56;
    int ow = n - oh * 56;
    pixb[q] = (oh + 1) * PH + (ow + 1);
  }

  const __bf16* wtb = wt + (size_t)b * 9 * CO * CI;
  const __bf16* itb = it + (size_t)b * PPIX * CI;

  f32x4 acc[4][4] = {};
  const int wm = (w >> 1) * 64;
  const int wn = (w & 1) * 64;

  for (int p = 0; p < 9; ++p) {
    const int kh = p / 3, kw = p - kh * 3;
    const int poff = kh * PH + kw - (PH + 1);   // pix = pixb + poff
    const __bf16* wtp = wtb + p * CO * CI;
    for (int ci0 = 0; ci0 < CI; ci0 += 32) {
      // ---- stage: wave w fills ko=w for both row-halves of A and B ----
#pragma unroll
      for (int q = 0; q < 2; ++q) {
        const __bf16* ga = wtp + (q * 64 + lane) * CI + ci0 + w * 8;
        glds16(ga, &As[w * 1024 + q * 512]);
        const __bf16* gb = itb + (size_t)(pixb[q] + poff) * CI + ci0 + w * 8;
        glds16(gb, &Bs[w * 1024 + q * 512]);
      }
      __syncthreads();
      // ---- compute: 4x4 frags of 16x16x32 ----
      bf16x8 af[4], bf[4];
#pragma unroll
      for (int mf = 0; mf < 4; ++mf)
        af[mf] = *(const bf16x8*)&As[quad * 1024 + (wm + mf * 16 + l15) * 8];
#pragma unroll
      for (int nf = 0; nf < 4; ++nf)
        bf[nf] = *(const bf16x8*)&Bs[quad * 1024 + (wn + nf * 16 + l15) * 8];
#pragma unroll
      for (int mf = 0; mf < 4; ++mf)
#pragma unroll
        for (int nf = 0; nf < 4; ++nf)
          acc[mf][nf] = __builtin_amdgcn_mfma_f32_16x16x32_bf16(
              af[mf], bf[nf], acc[mf][nf], 0, 0, 0);
      __syncthreads();
    }
  }

  // ---- epilogue: C[row=co][col=n], col = lane&15, row = quad*4 + reg ----
  float* ob = out + (size_t)b * CO * NPIX;
#pragma unroll
  for (int mf = 0; mf < 4; ++mf) {
#pragma unroll
    for (int nf = 0; nf < 4; ++nf) {
      int n = nt * 128 + wn + nf * 16 + l15;
      if (n < NPIX) {
#pragma unroll
        for (int r = 0; r < 4; ++r) {
          int co = wm + mf * 16 + quad * 4 + r;
          ob[(size_t)co * NPIX + n] = acc[mf][nf][r];
        }
      }
    }
  }
}

// ---------------------------------------------------------------------------
extern "C" void kernel_launch(void* const* d_in, const int* in_sizes, int n_in,
                              void* d_out, int out_size, void* d_ws, size_t ws_size,
                              hipStream_t stream) {
  const float* inp = (const float*)d_in[0];   // [32,128,56,56]
  const float* eps = (const float*)d_in[1];   // [32,128,128,3,3]
  const float* psi = (const float*)d_in[2];   // [128,128,3,3]
  const float* mu  = (const float*)d_in[3];   // [128,128,3,3]

  // ws layout: wt (9,437,184 B) | inp_t (27,557,888 B)  -> 36,995,072 B total
  __bf16* wt = (__bf16*)d_ws;
  __bf16* it = (__bf16*)((char*)d_ws + 9437184);

  prep_weights<<<18432, 256, 0, stream>>>(eps, psi, mu, wt);
  border_zero<<<456, 256, 0, stream>>>(it);
  transpose_pad<<<dim3(49, 32), 256, 0, stream>>>(inp, it);
  bconv_gemm<<<dim3(NT, 32), 256, 0, stream>>>(wt, it, (float*)d_out);
}